// Round 9
// baseline (165.492 us; speedup 1.0000x reference)
//
#include <hip/hip_runtime.h>
#include <math.h>
#include <stdint.h>

#define B_ 4
#define S_ 1024
#define F_ 512    // W*DIM = HEADS*HD
#define HD 128
#define SOFT_C 4.0f   // fixed exp-centering; |S| << 88 so no running max needed

typedef __attribute__((ext_vector_type(8))) short short8;
typedef __attribute__((ext_vector_type(4))) float f32x4;
typedef __attribute__((ext_vector_type(4))) unsigned int u32x4;
typedef __attribute__((ext_vector_type(2))) unsigned int u32x2;

__device__ __forceinline__ unsigned short f2bf(float f) {
    unsigned int u = __float_as_uint(f);
    u = (u + 0x7FFFu + ((u >> 16) & 1u)) >> 16;
    return (unsigned short)u;
}
__device__ __forceinline__ float bf2f(unsigned int s) {
    return __uint_as_float(s << 16);
}
__device__ __forceinline__ void pack_hilo(const float* v, u32x4& hi, u32x4& lo) {
    #pragma unroll
    for (int p = 0; p < 4; ++p) {
        unsigned int h0 = f2bf(v[2 * p]), h1 = f2bf(v[2 * p + 1]);
        float l0 = v[2 * p] - bf2f(h0), l1 = v[2 * p + 1] - bf2f(h1);
        hi[p] = h0 | (h1 << 16);
        lo[p] = (unsigned int)f2bf(l0) | ((unsigned int)f2bf(l1) << 16);
    }
}

// ---------------------------------------------------------------------------
// K0 k_prep: blk 0-3: pack {qw*scale, kw, vw, ow} -> bf16 hi/lo arrays.
//            blk 4-7: normalized pos-softmax p[b][h][t] (no-max exp).
//            blk 8  : strength vector sv / svq(=sv*scale).
// ---------------------------------------------------------------------------
__global__ __launch_bounds__(256) void k_prep(
    const int* __restrict__ embed_id,
    const float* __restrict__ qw, const float* __restrict__ kw,
    const float* __restrict__ vw, const float* __restrict__ ow,
    const float* __restrict__ pos,
    const float* __restrict__ pw1, const float* __restrict__ pb1,
    const float* __restrict__ pw2, const float* __restrict__ pb2,
    const float* __restrict__ head_w,
    const float* __restrict__ strength, const float* __restrict__ str_w,
    const float* __restrict__ str_b,
    unsigned short* __restrict__ packs,
    float* __restrict__ sv, float* __restrict__ svq,
    float* __restrict__ p_g)
{
    __shared__ float red_s[4][4];
    __shared__ float inv_s[4];
    const int blk = blockIdx.x, tid = threadIdx.x;
    const float SCALE = 0.08838834764831845f;

    if (blk < 4) {
        const int id = embed_id[0];
        const float* src = (blk == 0 ? qw + id * 4096 : blk == 1 ? kw + id * 4096
                            : blk == 2 ? vw + id * 4096 : ow);
        const float scale = (blk == 0) ? SCALE : 1.0f;
        unsigned short* hi = packs + blk * 8192;
        unsigned short* lo = hi + 4096;
        for (int i = tid; i < 4096; i += 256) {
            float v = src[i] * scale;
            unsigned short h = f2bf(v);
            hi[i] = h;
            lo[i] = f2bf(v - bf2f(h));
        }
    } else if (blk < 8) {
        const int b = blk - 4;
        const int wv = tid >> 6;
        float w1_[9], b1_[3], w2_[24], b2_[8], hw_[32];
        #pragma unroll
        for (int i = 0; i < 9; ++i)  w1_[i] = pw1[i];
        #pragma unroll
        for (int i = 0; i < 3; ++i)  b1_[i] = pb1[i];
        #pragma unroll
        for (int i = 0; i < 24; ++i) w2_[i] = pw2[i];
        #pragma unroll
        for (int i = 0; i < 8; ++i)  b2_[i] = pb2[i];
        #pragma unroll
        for (int i = 0; i < 32; ++i) hw_[i] = head_w[i];

        float ev[4][4];
        float ps[4] = {0.f, 0.f, 0.f, 0.f};
        #pragma unroll
        for (int k = 0; k < 4; ++k) {
            const int t = k * 256 + tid;
            float p0 = pos[(b * S_ + t) * 3 + 0];
            float p1 = pos[(b * S_ + t) * 3 + 1];
            float p2 = pos[(b * S_ + t) * 3 + 2];
            float h0 = fmaxf(0.f, p0 * w1_[0] + p1 * w1_[1] + p2 * w1_[2] + b1_[0]);
            float h1 = fmaxf(0.f, p0 * w1_[3] + p1 * w1_[4] + p2 * w1_[5] + b1_[1]);
            float h2 = fmaxf(0.f, p0 * w1_[6] + p1 * w1_[7] + p2 * w1_[8] + b1_[2]);
            float ph[8];
            #pragma unroll
            for (int o8 = 0; o8 < 8; ++o8)
                ph[o8] = h0 * w2_[o8 * 3] + h1 * w2_[o8 * 3 + 1] + h2 * w2_[o8 * 3 + 2] + b2_[o8];
            #pragma unroll
            for (int h = 0; h < 4; ++h) {
                float A = 0.f;
                #pragma unroll
                for (int o8 = 0; o8 < 8; ++o8) A += ph[o8] * hw_[h * 8 + o8];
                ev[k][h] = __expf(-A - 1.0f);
                ps[h] += ev[k][h];
            }
        }
        #pragma unroll
        for (int h = 0; h < 4; ++h)
            #pragma unroll
            for (int off = 1; off < 64; off <<= 1)
                ps[h] += __shfl_xor(ps[h], off);
        if ((tid & 63) == 0)
            #pragma unroll
            for (int h = 0; h < 4; ++h) red_s[wv][h] = ps[h];
        __syncthreads();
        if (tid < 4)
            inv_s[tid] = 1.f / (red_s[0][tid] + red_s[1][tid] + red_s[2][tid] + red_s[3][tid]);
        __syncthreads();
        #pragma unroll
        for (int k = 0; k < 4; ++k)
            #pragma unroll
            for (int h = 0; h < 4; ++h)
                p_g[(b * 4 + h) * S_ + k * 256 + tid] = ev[k][h] * inv_s[h];
    } else {
        __shared__ float part_s[4][64];
        const int c = tid & 63, pr = tid >> 6;
        const float* wrow = str_w + c * 512 + pr * 128;
        const float* st   = strength + pr * 128;
        float acc = 0.f;
        #pragma unroll
        for (int j4 = 0; j4 < 32; ++j4) {
            f32x4 wv4 = *(const f32x4*)(wrow + j4 * 4);
            f32x4 s4  = *(const f32x4*)(st + j4 * 4);
            acc += wv4[0] * s4[0] + wv4[1] * s4[1] + wv4[2] * s4[2] + wv4[3] * s4[3];
        }
        part_s[pr][c] = acc;
        __syncthreads();
        if (tid < 64) {
            float v = part_s[0][tid] + part_s[1][tid] + part_s[2][tid]
                    + part_s[3][tid] + str_b[tid];
            sv[tid] = v;
            svq[tid] = v * SCALE;
        }
    }
}

// ---------------------------------------------------------------------------
// K1 k_qkv: QKV MFMA GEMM from PREPACKED bf16 emb (no per-wave fp32 reload /
// repack, no strength GEMV).  Q/K operand-swapped (lane = channel,
// contiguous stores); V lane = row into tile-blocked yvt2.
//   yqh/ykh[bh][s][d=128] ; yvt2[bh][s/64][d][s%64]
// blk>=512: xbar[b][w][c] = sum_s p[b,h(w),s]*x[b,c,s,w]  (pos branch).
// ---------------------------------------------------------------------------
__global__ __launch_bounds__(256) void k_qkv(
    const float* __restrict__ x,
    const unsigned short* __restrict__ packs,
    const float* __restrict__ sv, const float* __restrict__ svq,
    const float* __restrict__ p_g,
    unsigned short* __restrict__ yqh, unsigned short* __restrict__ ykh,
    unsigned short* __restrict__ yvt2, float* __restrict__ xbar)
{
    __shared__ float xr_s[4][8];
    const int tid  = threadIdx.x;
    const int wv   = tid >> 6;
    const int lane = tid & 63;
    const int quad = lane >> 4;
    const int l15  = lane & 15;

    if (blockIdx.x >= 512) {
        const int bi = blockIdx.x - 512;
        const int b = bi >> 6, c = bi & 63;
        const float* xc = x + (size_t)b * 524288 + c * 8192;
        const float* pb = p_g + b * 4096;
        float acc[8] = {};
        #pragma unroll
        for (int rr = 0; rr < 4; ++rr) {
            const int s = tid * 4 + rr;
            f32x4 x0 = *(const f32x4*)(xc + s * 8);
            f32x4 x1 = *(const f32x4*)(xc + s * 8 + 4);
            float p0 = pb[s], p1 = pb[1024 + s], p2 = pb[2048 + s], p3 = pb[3072 + s];
            acc[0] += p0 * x0[0]; acc[1] += p0 * x0[1];
            acc[2] += p1 * x0[2]; acc[3] += p1 * x0[3];
            acc[4] += p2 * x1[0]; acc[5] += p2 * x1[1];
            acc[6] += p3 * x1[2]; acc[7] += p3 * x1[3];
        }
        #pragma unroll
        for (int j = 0; j < 8; ++j)
            #pragma unroll
            for (int off = 1; off < 64; off <<= 1)
                acc[j] += __shfl_xor(acc[j], off);
        if (lane == 0)
            #pragma unroll
            for (int j = 0; j < 8; ++j) xr_s[wv][j] = acc[j];
        __syncthreads();
        if (tid < 8)
            xbar[(b * 8 + tid) * 64 + c] = xr_s[0][tid] + xr_s[1][tid]
                                         + xr_s[2][tid] + xr_s[3][tid];
        return;
    }

    const int r0   = blockIdx.x * 64 + wv * 16;
    const int b    = r0 >> 13;
    const int rloc = (r0 & 8191) + l15;
    const float* xb = x + (size_t)b * 524288;

    // x fragments (rows on l15), hi/lo split
    u32x4 xhi[2], xlo[2];
    #pragma unroll
    for (int kc = 0; kc < 2; ++kc) {
        float xv[8];
        #pragma unroll
        for (int j = 0; j < 8; ++j)
            xv[j] = xb[(kc * 32 + quad * 8 + j) * 8192 + rloc];
        pack_hilo(xv, xhi[kc], xlo[kc]);
    }

    // per-lane strength (channel = nt*16+l15) for Q/K; per-reg for V
    float svq_l[4], sv_l[4];
    #pragma unroll
    for (int nt = 0; nt < 4; ++nt) {
        svq_l[nt] = svq[nt * 16 + l15];
        sv_l[nt]  = sv[nt * 16 + l15];
    }
    f32x4 svA[4];
    #pragma unroll
    for (int mt = 0; mt < 4; ++mt)
        svA[mt] = *(const f32x4*)(sv + mt * 16 + quad * 4);

    // Q/K store geometry (row = r0 + quad*4 + rr, lane = channel)
    int idxq[4];
    #pragma unroll
    for (int rr = 0; rr < 4; ++rr) {
        const int rl = quad * 4 + rr;
        const int w_ = rl & 7;
        const int s_loc = ((r0 & 8191) >> 3) + (rl >> 3);
        idxq[rr] = (b * 4 + (w_ >> 1)) * 131072 + s_loc * 128 + (w_ & 1) * 64 + l15;
    }
    // V store geometry (lane = row)
    const int row_g = r0 + l15;
    const int s_idx = (row_g >> 3) & 1023;
    const int w_idx = row_g & 7;
    const int bh    = b * 4 + (w_idx >> 1);
    const int dbase = (w_idx & 1) * 64;
    unsigned short* vtb = yvt2 + (size_t)bh * 131072 + (s_idx >> 6) * 8192
                        + (size_t)dbase * 64 + (s_idx & 63);

    #pragma unroll
    for (int mat = 0; mat < 2; ++mat) {
        const unsigned short* mh = packs + mat * 8192;
        const unsigned short* ml = mh + 4096;
        f32x4 acc[4] = {};
        #pragma unroll
        for (int kc = 0; kc < 2; ++kc)
            #pragma unroll
            for (int nt = 0; nt < 4; ++nt) {
                const int off = (nt * 16 + l15) * 64 + kc * 32 + quad * 8;
                u32x4 ehi = *(const u32x4*)(mh + off);
                u32x4 elo = *(const u32x4*)(ml + off);
                acc[nt] = __builtin_amdgcn_mfma_f32_16x16x32_bf16(
                    __builtin_bit_cast(short8, xhi[kc]),
                    __builtin_bit_cast(short8, ehi), acc[nt], 0, 0, 0);
                acc[nt] = __builtin_amdgcn_mfma_f32_16x16x32_bf16(
                    __builtin_bit_cast(short8, xlo[kc]),
                    __builtin_bit_cast(short8, ehi), acc[nt], 0, 0, 0);
                acc[nt] = __builtin_amdgcn_mfma_f32_16x16x32_bf16(
                    __builtin_bit_cast(short8, xhi[kc]),
                    __builtin_bit_cast(short8, elo), acc[nt], 0, 0, 0);
            }
        unsigned short* y = (mat == 0 ? yqh : ykh);
        const float* svp = (mat == 0 ? svq_l : sv_l);
        #pragma unroll
        for (int nt = 0; nt < 4; ++nt)
            #pragma unroll
            for (int rr = 0; rr < 4; ++rr)
                y[(size_t)idxq[rr] + nt * 16] = f2bf(acc[nt][rr] + svp[nt]);
    }
    {
        const unsigned short* mh = packs + 2 * 8192;
        const unsigned short* ml = mh + 4096;
        f32x4 acc[4] = {};
        #pragma unroll
        for (int kc = 0; kc < 2; ++kc)
            #pragma unroll
            for (int mt = 0; mt < 4; ++mt) {
                const int off = (mt * 16 + l15) * 64 + kc * 32 + quad * 8;
                u32x4 ehi = *(const u32x4*)(mh + off);
                u32x4 elo = *(const u32x4*)(ml + off);
                acc[mt] = __builtin_amdgcn_mfma_f32_16x16x32_bf16(
                    __builtin_bit_cast(short8, ehi),
                    __builtin_bit_cast(short8, xhi[kc]), acc[mt], 0, 0, 0);
                acc[mt] = __builtin_amdgcn_mfma_f32_16x16x32_bf16(
                    __builtin_bit_cast(short8, ehi),
                    __builtin_bit_cast(short8, xlo[kc]), acc[mt], 0, 0, 0);
                acc[mt] = __builtin_amdgcn_mfma_f32_16x16x32_bf16(
                    __builtin_bit_cast(short8, elo),
                    __builtin_bit_cast(short8, xhi[kc]), acc[mt], 0, 0, 0);
            }
        #pragma unroll
        for (int mt = 0; mt < 4; ++mt)
            #pragma unroll
            for (int rr = 0; rr < 4; ++rr) {
                const int c = mt * 16 + quad * 4 + rr;
                vtb[(size_t)c * 64] = f2bf(acc[mt][rr] + svA[mt][rr]);
            }
    }
}

// ---------------------------------------------------------------------------
// K2 k_attn: single-buffered LDS flash attention, 4 blocks/CU (37KB LDS).
// Grid 1024 = 16 bh x 64 q-tiles (16 rows).  Block 4 waves = (t-half th,
// d-half dh); registers hold the next tile (prefetch) so a single LDS buffer
// suffices: write -> barrier -> compute -> barrier.  th partials (o, l)
// combined through LDS; th=0 waves run the fused out-projection epilogue
// (prepacked out_w).  No-max softmax, quad-shuffle P transpose.
// ---------------------------------------------------------------------------
__global__ __launch_bounds__(256, 4) void k_attn(
    const unsigned short* __restrict__ yqh, const unsigned short* __restrict__ ykh,
    const unsigned short* __restrict__ yvt2,
    const float* __restrict__ xbar, const float* __restrict__ vw,
    const int* __restrict__ embed_id, const float* __restrict__ sv_g,
    const float* __restrict__ gate,
    const unsigned short* __restrict__ packs,
    const float* __restrict__ ow, const float* __restrict__ ob,
    float* __restrict__ out)
{
    __shared__ __align__(16) unsigned short kx[64 * 136];   // 17408 B
    __shared__ __align__(16) unsigned short vx[128 * 72];   // 18432 B
    __shared__ float vbar_s[128];
    __shared__ float vproj_s[128];
    __shared__ float lsh[2][16];

    const int tid  = threadIdx.x;
    const int w    = tid >> 6;
    const int lane = tid & 63;
    const int quad = lane >> 4;
    const int l15  = lane & 15;
    const int bh = blockIdx.x & 15, qt = blockIdx.x >> 4;
    const int b = bh >> 2, h = bh & 3;
    const int s0 = qt * 16;
    const int th = w >> 1;        // t-half (512 t)
    const int dh = w & 1;         // d-half (64 cols)

    const unsigned short* ykb = ykh + (size_t)bh * 131072;
    const unsigned short* yvb = yvt2 + (size_t)bh * 131072;
    const float gf = 1.f / (1.f + __expf(-gate[h]));

    // ---- vbar prologue (pos branch, rank-1 reconstruction) ----
    if (tid < 128) {
        const int c = tid & 63, wloc = tid >> 6;
        const float* ver = vw + embed_id[0] * 4096 + c * 64;
        const float* xbr = xbar + (b * 8 + h * 2 + wloc) * 64;
        float a = sv_g[c];
        #pragma unroll
        for (int j4 = 0; j4 < 16; ++j4) {
            f32x4 e4 = *(const f32x4*)(ver + j4 * 4);
            f32x4 x4 = *(const f32x4*)(xbr + j4 * 4);
            a += e4[0] * x4[0] + e4[1] * x4[1] + e4[2] * x4[2] + e4[3] * x4[3];
        }
        vbar_s[wloc * 64 + c] = a;
    }

    // ---- Q fragments: B[n=q(l15)][k=d], full 128-d contraction ----
    u32x4 qf[4];
    #pragma unroll
    for (int kc = 0; kc < 4; ++kc)
        qf[kc] = *(const u32x4*)(yqh + (size_t)bh * 131072
                 + (s0 + l15) * 128 + kc * 32 + quad * 8);

    // ---- prefetch tile 0 into registers ----
    u32x4 kst[4], vst[4];
    #pragma unroll
    for (int r = 0; r < 4; ++r) {
        kst[r] = *(const u32x4*)(ykb + r * 2048 + tid * 8);
        vst[r] = *(const u32x4*)(yvb + r * 2048 + tid * 8);
    }

    __syncthreads();   // vbar_s visible
    // ---- vproj = gf*(vbar_dh @ ow^T) + ob  (fp32, once per block) ----
    if (tid < 128) {
        const int cp = tid & 63, w2 = tid >> 6;
        const float* owr = ow + cp * 64;
        const float* vb = vbar_s + w2 * 64;
        float a = 0.f;
        #pragma unroll
        for (int j4 = 0; j4 < 16; ++j4) {
            f32x4 o4 = *(const f32x4*)(owr + j4 * 4);
            f32x4 v4 = *(const f32x4*)(vb + j4 * 4);
            a += o4[0] * v4[0] + o4[1] * v4[1] + o4[2] * v4[2] + o4[3] * v4[3];
        }
        vproj_s[tid] = gf * a + ob[cp];
    }

    f32x4 o[4] = {};
    float lsum = 0.f;
    const int srcA = ((quad & 1) << 5) + l15;
    const int t0loc = th * 32;

    for (int it = 0; it < 16; ++it) {
        // write staged registers to the single LDS buffer
        #pragma unroll
        for (int r = 0; r < 4; ++r) {
            const int off = r * 2048 + tid * 8;
            *(u32x4*)&kx[(off >> 7) * 136 + (off & 127)] = kst[r];
            *(u32x4*)&vx[(off >> 6) * 72 + (off & 63)] = vst[r];
        }
        __syncthreads();
        // issue next tile's global loads (land in regs during compute)
        if (it < 15) {
            const unsigned short* ksrc = ykb + (it + 1) * 8192;
            const unsigned short* vsrc = yvb + (it + 1) * 8192;
            #pragma unroll
            for (int r = 0; r < 4; ++r)
                kst[r] = *(const u32x4*)(ksrc + r * 2048 + tid * 8);
            #pragma unroll
            for (int r = 0; r < 4; ++r)
                vst[r] = *(const u32x4*)(vsrc + r * 2048 + tid * 8);
        }

        // ---- S^T = K Q^T over this wave's two 16-t subtiles ----
        f32x4 sa0 = {}, sa1 = {};
        #pragma unroll
        for (int kc = 0; kc < 4; ++kc) {
            u32x4 a0 = *(const u32x4*)&kx[(t0loc + l15) * 136 + kc * 32 + quad * 8];
            sa0 = __builtin_amdgcn_mfma_f32_16x16x32_bf16(
                __builtin_bit_cast(short8, a0),
                __builtin_bit_cast(short8, qf[kc]), sa0, 0, 0, 0);
        }
        #pragma unroll
        for (int kc = 0; kc < 4; ++kc) {
            u32x4 a1 = *(const u32x4*)&kx[(t0loc + 16 + l15) * 136 + kc * 32 + quad * 8];
            sa1 = __builtin_amdgcn_mfma_f32_16x16x32_bf16(
                __builtin_bit_cast(short8, a1),
                __builtin_bit_cast(short8, qf[kc]), sa1, 0, 0, 0);
        }

        // p = exp(S - C); per-lane l partial (lane l15 = q-row)
        float p0[4], p1[4];
        #pragma unroll
        for (int r = 0; r < 4; ++r) {
            p0[r] = __expf(sa0[r] - SOFT_C);
            p1[r] = __expf(sa1[r] - SOFT_C);
            lsum += p0[r] + p1[r];
        }

        // P (C-layout) -> B-frag of PV^T via quad-permute shuffles
        unsigned int pk00 = (unsigned int)f2bf(p0[0]) | ((unsigned int)f2bf(p0[1]) << 16);
        unsigned int pk01 = (unsigned int)f2bf(p0[2]) | ((unsigned int)f2bf(p0[3]) << 16);
        unsigned int pk10 = (unsigned int)f2bf(p1[0]) | ((unsigned int)f2bf(p1[1]) << 16);
        unsigned int pk11 = (unsigned int)f2bf(p1[2]) | ((unsigned int)f2bf(p1[3]) << 16);
        unsigned int sel0 = (quad < 2) ? pk00 : pk10;
        unsigned int sel1 = (quad < 2) ? pk01 : pk11;
        u32x4 pf;
        pf[0] = (unsigned int)__shfl((int)sel0, srcA);
        pf[1] = (unsigned int)__shfl((int)sel1, srcA);
        pf[2] = (unsigned int)__shfl((int)sel0, srcA + 16);
        pf[3] = (unsigned int)__shfl((int)sel1, srcA + 16);

        // O^T += V^T P^T  (A = V from LDS, m = d)
        #pragma unroll
        for (int dt = 0; dt < 4; ++dt) {
            u32x4 vf = *(const u32x4*)&vx[(dh * 64 + dt * 16 + l15) * 72
                                           + t0loc + quad * 8];
            o[dt] = __builtin_amdgcn_mfma_f32_16x16x32_bf16(
                __builtin_bit_cast(short8, vf),
                __builtin_bit_cast(short8, pf), o[dt], 0, 0, 0);
        }
        __syncthreads();   // all reads done before next iter's writes
    }

    // ---- combine t-halves: th=1 parks partials, th=0 reduces ----
    lsum += __shfl_xor(lsum, 16);
    lsum += __shfl_xor(lsum, 32);
    float* cmb = (float*)kx;
    if (th == 1) {
        #pragma unroll
        for (int dt = 0; dt < 4; ++dt)
            *(f32x4*)&cmb[(dh * 16 + l15) * 68 + dt * 16 + quad * 4] = o[dt];
        if (quad == 0) lsh[dh][l15] = lsum;
    }
    __syncthreads();
    if (th == 0) {
        #pragma unroll
        for (int dt = 0; dt < 4; ++dt) {
            f32x4 p = *(const f32x4*)&cmb[(dh * 16 + l15) * 68 + dt * 16 + quad * 4];
            o[dt] += p;
        }
        lsum += lsh[dh][l15];
        const float cf = (1.f - gf) / lsum;

        // ---- fused output projection (prepacked out_w) ----
        unsigned short* yst = (unsigned short*)vx + dh * 4352;  // hi:[q][68], lo at +1088
        #pragma unroll
        for (int dt = 0; dt < 4; ++dt) {
            unsigned int hh[4];
            unsigned short ll[4];
            #pragma unroll
            for (int r = 0; r < 4; ++r) {
                float y = cf * o[dt][r];
                hh[r] = f2bf(y);
                ll[r] = f2bf(y - bf2f(hh[r]));
            }
            const int dloc = dt * 16 + quad * 4;
            u32x2 ph_, pl_;
            ph_[0] = hh[0] | (hh[1] << 16);
            ph_[1] = hh[2] | (hh[3] << 16);
            pl_[0] = (unsigned int)ll[0] | ((unsigned int)ll[1] << 16);
            pl_[1] = (unsigned int)ll[2] | ((unsigned int)ll[3] << 16);
            *(u32x2*)&yst[l15 * 68 + dloc] = ph_;
            *(u32x2*)&yst[1088 + l15 * 68 + dloc] = pl_;
        }
        u32x4 ybh[2], ybl[2];
        #pragma unroll
        for (int kc = 0; kc < 2; ++kc) {
            ybh[kc] = *(const u32x4*)&yst[l15 * 68 + kc * 32 + quad * 8];
            ybl[kc] = *(const u32x4*)&yst[1088 + l15 * 68 + kc * 32 + quad * 8];
        }
        const unsigned short* owh = packs + 3 * 8192;
        const unsigned short* owl = owh + 4096;
        f32x4 accp[4] = {};
        #pragma unroll
        for (int kc = 0; kc < 2; ++kc)
            #pragma unroll
            for (int mt = 0; mt < 4; ++mt) {
                const int off = (mt * 16 + l15) * 64 + kc * 32 + quad * 8;
                u32x4 ahi = *(const u32x4*)(owh + off);
                u32x4 alo = *(const u32x4*)(owl + off);
                accp[mt] = __builtin_amdgcn_mfma_f32_16x16x32_bf16(
                    __builtin_bit_cast(short8, ahi),
                    __builtin_bit_cast(short8, ybh[kc]), accp[mt], 0, 0, 0);
                accp[mt] = __builtin_amdgcn_mfma_f32_16x16x32_bf16(
                    __builtin_bit_cast(short8, ahi),
                    __builtin_bit_cast(short8, ybl[kc]), accp[mt], 0, 0, 0);
                accp[mt] = __builtin_amdgcn_mfma_f32_16x16x32_bf16(
                    __builtin_bit_cast(short8, alo),
                    __builtin_bit_cast(short8, ybh[kc]), accp[mt], 0, 0, 0);
            }
        const int sQ = s0 + l15;
        float* op = out + ((size_t)((b * S_ + sQ) * 8 + 2 * h + dh)) * 64;
        #pragma unroll
        for (int mt = 0; mt < 4; ++mt) {
            f32x4 vp = *(const f32x4*)&vproj_s[dh * 64 + mt * 16 + quad * 4];
            f32x4 rv = accp[mt] + vp;
            *(f32x4*)(op + mt * 16 + quad * 4) = rv;
        }
    }
}

extern "C" void kernel_launch(void* const* d_in, const int* in_sizes, int n_in,
                              void* d_out, int out_size, void* d_ws, size_t ws_size,
                              hipStream_t stream) {
    (void)in_sizes; (void)n_in; (void)out_size; (void)ws_size;
    const float* x        = (const float*)d_in[0];
    const float* pos      = (const float*)d_in[1];
    const float* strength = (const float*)d_in[2];
    const int*   embed_id = (const int*)d_in[3];
    const float* qw       = (const float*)d_in[4];
    const float* kw       = (const float*)d_in[5];
    const float* vw       = (const float*)d_in[6];
    const float* pw1      = (const float*)d_in[7];
    const float* pb1      = (const float*)d_in[8];
    const float* pw2      = (const float*)d_in[9];
    const float* pb2      = (const float*)d_in[10];
    const float* head_w   = (const float*)d_in[11];
    const float* gate     = (const float*)d_in[13];
    const float* out_w    = (const float*)d_in[14];
    const float* out_b    = (const float*)d_in[15];
    const float* str_w    = (const float*)d_in[16];
    const float* str_b    = (const float*)d_in[17];
    float* out = (float*)d_out;

    unsigned short* yqh   = (unsigned short*)d_ws;         // 4 MiB
    unsigned short* ykh   = yqh + 2097152;                 // 4 MiB
    unsigned short* yvt2  = ykh + 2097152;                 // 4 MiB
    unsigned short* packs = yvt2 + 2097152;                // 8 x 4096 shorts
    float* sv   = (float*)(packs + 8 * 4096);              // 64
    float* svq  = sv + 64;                                 // 64
    float* p_g  = svq + 64;                                // 16384
    float* xbar = p_g + 16384;                             // 2048

    k_prep<<<9, 256, 0, stream>>>(embed_id, qw, kw, vw, out_w, pos,
                                  pw1, pb1, pw2, pb2, head_w,
                                  strength, str_w, str_b, packs, sv, svq, p_g);
    k_qkv<<<768, 256, 0, stream>>>(x, packs, sv, svq, p_g, yqh, ykh, yvt2, xbar);
    k_attn<<<1024, 256, 0, stream>>>(yqh, ykh, yvt2, xbar, vw, embed_id, sv,
                                     gate, packs, out_w, out_b, out);
}

// Round 10
// 160.398 us; speedup vs baseline: 1.0318x; 1.0318x over previous
//
#include <hip/hip_runtime.h>
#include <math.h>
#include <stdint.h>

#define B_ 4
#define S_ 1024
#define F_ 512
#define HD 128
#define SOFT_C 4.0f   // fixed exp-centering; |S| << 88 so no running max needed

typedef __attribute__((ext_vector_type(8))) short short8;
typedef __attribute__((ext_vector_type(4))) float f32x4;
typedef __attribute__((ext_vector_type(4))) unsigned int u32x4;
typedef __attribute__((ext_vector_type(2))) unsigned int u32x2;

__device__ __forceinline__ unsigned short f2bf(float f) {
    unsigned int u = __float_as_uint(f);
    u = (u + 0x7FFFu + ((u >> 16) & 1u)) >> 16;
    return (unsigned short)u;
}
__device__ __forceinline__ float bf2f(unsigned int s) {
    return __uint_as_float(s << 16);
}
__device__ __forceinline__ void pack_hilo(const float* v, u32x4& hi, u32x4& lo) {
    #pragma unroll
    for (int p = 0; p < 4; ++p) {
        unsigned int h0 = f2bf(v[2 * p]), h1 = f2bf(v[2 * p + 1]);
        float l0 = v[2 * p] - bf2f(h0), l1 = v[2 * p + 1] - bf2f(h1);
        hi[p] = h0 | (h1 << 16);
        lo[p] = (unsigned int)f2bf(l0) | ((unsigned int)f2bf(l1) << 16);
    }
}

// ---------------------------------------------------------------------------
// K0 k_prep: blk 0-3: pack {qw*scale, kw, vw, ow} -> bf16 hi/lo arrays.
//            blk 4-7: normalized pos-softmax p[b][h][t].  blk 8: sv/svq.
// ---------------------------------------------------------------------------
__global__ __launch_bounds__(256) void k_prep(
    const int* __restrict__ embed_id,
    const float* __restrict__ qw, const float* __restrict__ kw,
    const float* __restrict__ vw, const float* __restrict__ ow,
    const float* __restrict__ pos,
    const float* __restrict__ pw1, const float* __restrict__ pb1,
    const float* __restrict__ pw2, const float* __restrict__ pb2,
    const float* __restrict__ head_w,
    const float* __restrict__ strength, const float* __restrict__ str_w,
    const float* __restrict__ str_b,
    unsigned short* __restrict__ packs,
    float* __restrict__ sv, float* __restrict__ svq,
    float* __restrict__ p_g)
{
    __shared__ float red_s[4][4];
    __shared__ float inv_s[4];
    const int blk = blockIdx.x, tid = threadIdx.x;
    const float SCALE = 0.08838834764831845f;

    if (blk < 4) {
        const int id = embed_id[0];
        const float* src = (blk == 0 ? qw + id * 4096 : blk == 1 ? kw + id * 4096
                            : blk == 2 ? vw + id * 4096 : ow);
        const float scale = (blk == 0) ? SCALE : 1.0f;
        unsigned short* hi = packs + blk * 8192;
        unsigned short* lo = hi + 4096;
        for (int i = tid; i < 4096; i += 256) {
            float v = src[i] * scale;
            unsigned short h = f2bf(v);
            hi[i] = h;
            lo[i] = f2bf(v - bf2f(h));
        }
    } else if (blk < 8) {
        const int b = blk - 4;
        const int wv = tid >> 6;
        float w1_[9], b1_[3], w2_[24], b2_[8], hw_[32];
        #pragma unroll
        for (int i = 0; i < 9; ++i)  w1_[i] = pw1[i];
        #pragma unroll
        for (int i = 0; i < 3; ++i)  b1_[i] = pb1[i];
        #pragma unroll
        for (int i = 0; i < 24; ++i) w2_[i] = pw2[i];
        #pragma unroll
        for (int i = 0; i < 8; ++i)  b2_[i] = pb2[i];
        #pragma unroll
        for (int i = 0; i < 32; ++i) hw_[i] = head_w[i];

        float ev[4][4];
        float ps[4] = {0.f, 0.f, 0.f, 0.f};
        #pragma unroll
        for (int k = 0; k < 4; ++k) {
            const int t = k * 256 + tid;
            float p0 = pos[(b * S_ + t) * 3 + 0];
            float p1 = pos[(b * S_ + t) * 3 + 1];
            float p2 = pos[(b * S_ + t) * 3 + 2];
            float h0 = fmaxf(0.f, p0 * w1_[0] + p1 * w1_[1] + p2 * w1_[2] + b1_[0]);
            float h1 = fmaxf(0.f, p0 * w1_[3] + p1 * w1_[4] + p2 * w1_[5] + b1_[1]);
            float h2 = fmaxf(0.f, p0 * w1_[6] + p1 * w1_[7] + p2 * w1_[8] + b1_[2]);
            float ph[8];
            #pragma unroll
            for (int o8 = 0; o8 < 8; ++o8)
                ph[o8] = h0 * w2_[o8 * 3] + h1 * w2_[o8 * 3 + 1] + h2 * w2_[o8 * 3 + 2] + b2_[o8];
            #pragma unroll
            for (int h = 0; h < 4; ++h) {
                float A = 0.f;
                #pragma unroll
                for (int o8 = 0; o8 < 8; ++o8) A += ph[o8] * hw_[h * 8 + o8];
                ev[k][h] = __expf(-A - 1.0f);
                ps[h] += ev[k][h];
            }
        }
        #pragma unroll
        for (int h = 0; h < 4; ++h)
            #pragma unroll
            for (int off = 1; off < 64; off <<= 1)
                ps[h] += __shfl_xor(ps[h], off);
        if ((tid & 63) == 0)
            #pragma unroll
            for (int h = 0; h < 4; ++h) red_s[wv][h] = ps[h];
        __syncthreads();
        if (tid < 4)
            inv_s[tid] = 1.f / (red_s[0][tid] + red_s[1][tid] + red_s[2][tid] + red_s[3][tid]);
        __syncthreads();
        #pragma unroll
        for (int k = 0; k < 4; ++k)
            #pragma unroll
            for (int h = 0; h < 4; ++h)
                p_g[(b * 4 + h) * S_ + k * 256 + tid] = ev[k][h] * inv_s[h];
    } else {
        __shared__ float part_s[4][64];
        const int c = tid & 63, pr = tid >> 6;
        const float* wrow = str_w + c * 512 + pr * 128;
        const float* st   = strength + pr * 128;
        float acc = 0.f;
        #pragma unroll
        for (int j4 = 0; j4 < 32; ++j4) {
            f32x4 wv4 = *(const f32x4*)(wrow + j4 * 4);
            f32x4 s4  = *(const f32x4*)(st + j4 * 4);
            acc += wv4[0] * s4[0] + wv4[1] * s4[1] + wv4[2] * s4[2] + wv4[3] * s4[3];
        }
        part_s[pr][c] = acc;
        __syncthreads();
        if (tid < 64) {
            float v = part_s[0][tid] + part_s[1][tid] + part_s[2][tid]
                    + part_s[3][tid] + str_b[tid];
            sv[tid] = v;
            svq[tid] = v * SCALE;
        }
    }
}

// ---------------------------------------------------------------------------
// K1 k_qkv: QKV MFMA GEMM from prepacked emb.  NEW: K and V are stored
// PRE-FRAGMENTED so k_attn fragment loads are contiguous 1KB wave loads:
//   yqh[bh][s][128]  (Q row-major, loaded once per wave)
//   kfrag: K[s][dd] at (bh*64+(s>>4))*2048 + (dd>>3)*128 + (s&15)*8 + (dd&7)
//   vfrag: V[s][dd] at (bh*32+(s>>5))*4096 + (dd>>4)*512 + (dd&15)*32
//                      + ((s>>3)&3)*8 + (s&7)
// blk>=512: xbar blocks (pos branch weighted x-average).
// ---------------------------------------------------------------------------
__global__ __launch_bounds__(256) void k_qkv(
    const float* __restrict__ x,
    const unsigned short* __restrict__ packs,
    const float* __restrict__ sv, const float* __restrict__ svq,
    const float* __restrict__ p_g,
    unsigned short* __restrict__ yqh, unsigned short* __restrict__ kfrag,
    unsigned short* __restrict__ vfrag, float* __restrict__ xbar)
{
    __shared__ float xr_s[4][8];
    const int tid  = threadIdx.x;
    const int wv   = tid >> 6;
    const int lane = tid & 63;
    const int quad = lane >> 4;
    const int l15  = lane & 15;

    if (blockIdx.x >= 512) {
        const int bi = blockIdx.x - 512;
        const int b = bi >> 6, c = bi & 63;
        const float* xc = x + (size_t)b * 524288 + c * 8192;
        const float* pb = p_g + b * 4096;
        float acc[8] = {};
        #pragma unroll
        for (int rr = 0; rr < 4; ++rr) {
            const int s = tid * 4 + rr;
            f32x4 x0 = *(const f32x4*)(xc + s * 8);
            f32x4 x1 = *(const f32x4*)(xc + s * 8 + 4);
            float p0 = pb[s], p1 = pb[1024 + s], p2 = pb[2048 + s], p3 = pb[3072 + s];
            acc[0] += p0 * x0[0]; acc[1] += p0 * x0[1];
            acc[2] += p1 * x0[2]; acc[3] += p1 * x0[3];
            acc[4] += p2 * x1[0]; acc[5] += p2 * x1[1];
            acc[6] += p3 * x1[2]; acc[7] += p3 * x1[3];
        }
        #pragma unroll
        for (int j = 0; j < 8; ++j)
            #pragma unroll
            for (int off = 1; off < 64; off <<= 1)
                acc[j] += __shfl_xor(acc[j], off);
        if (lane == 0)
            #pragma unroll
            for (int j = 0; j < 8; ++j) xr_s[wv][j] = acc[j];
        __syncthreads();
        if (tid < 8)
            xbar[(b * 8 + tid) * 64 + c] = xr_s[0][tid] + xr_s[1][tid]
                                         + xr_s[2][tid] + xr_s[3][tid];
        return;
    }

    const int r0   = blockIdx.x * 64 + wv * 16;
    const int b    = r0 >> 13;
    const int rloc = (r0 & 8191) + l15;
    const float* xb = x + (size_t)b * 524288;

    // x fragments (rows on l15), hi/lo split
    u32x4 xhi[2], xlo[2];
    #pragma unroll
    for (int kc = 0; kc < 2; ++kc) {
        float xv[8];
        #pragma unroll
        for (int j = 0; j < 8; ++j)
            xv[j] = xb[(kc * 32 + quad * 8 + j) * 8192 + rloc];
        pack_hilo(xv, xhi[kc], xlo[kc]);
    }

    float svq_l[4], sv_l[4];
    #pragma unroll
    for (int nt = 0; nt < 4; ++nt) {
        svq_l[nt] = svq[nt * 16 + l15];
        sv_l[nt]  = sv[nt * 16 + l15];
    }
    f32x4 svA[4];
    #pragma unroll
    for (int mt = 0; mt < 4; ++mt)
        svA[mt] = *(const f32x4*)(sv + mt * 16 + quad * 4);

    // Q store geometry (row = r0 + quad*4 + rr, lane = channel)
    int idxq[4];
    // K fragment store base per rr (lane = channel, same row set)
    size_t idxk[4];
    #pragma unroll
    for (int rr = 0; rr < 4; ++rr) {
        const int rl = quad * 4 + rr;
        const int row_g2 = r0 + rl;
        const int s = (row_g2 & 8191) >> 3;
        const int w_ = row_g2 & 7;
        const int bh = ((row_g2 >> 13) * 4) + (w_ >> 1);
        idxq[rr] = (bh * 131072) + s * 128 + (w_ & 1) * 64 + l15;
        idxk[rr] = (size_t)(bh * 64 + (s >> 4)) * 2048 + (s & 15) * 8
                 + (w_ & 1) * 1024 + (l15 >> 3) * 128 + (l15 & 7);
    }
    // V fragment store base (lane = row)
    const int row_g = r0 + l15;
    const int s_idx = (row_g >> 3) & 1023;
    const int w_idx = row_g & 7;
    const int bhv   = (row_g >> 13) * 4 + (w_idx >> 1);
    const int dbase = (w_idx & 1) * 64;
    const size_t vbase = (size_t)(bhv * 32 + (s_idx >> 5)) * 4096
                       + ((s_idx >> 3) & 3) * 8 + (s_idx & 7);

    #pragma unroll
    for (int mat = 0; mat < 2; ++mat) {
        const unsigned short* mh = packs + mat * 8192;
        const unsigned short* ml = mh + 4096;
        f32x4 acc[4] = {};
        #pragma unroll
        for (int kc = 0; kc < 2; ++kc)
            #pragma unroll
            for (int nt = 0; nt < 4; ++nt) {
                const int off = (nt * 16 + l15) * 64 + kc * 32 + quad * 8;
                u32x4 ehi = *(const u32x4*)(mh + off);
                u32x4 elo = *(const u32x4*)(ml + off);
                acc[nt] = __builtin_amdgcn_mfma_f32_16x16x32_bf16(
                    __builtin_bit_cast(short8, xhi[kc]),
                    __builtin_bit_cast(short8, ehi), acc[nt], 0, 0, 0);
                acc[nt] = __builtin_amdgcn_mfma_f32_16x16x32_bf16(
                    __builtin_bit_cast(short8, xlo[kc]),
                    __builtin_bit_cast(short8, ehi), acc[nt], 0, 0, 0);
                acc[nt] = __builtin_amdgcn_mfma_f32_16x16x32_bf16(
                    __builtin_bit_cast(short8, xhi[kc]),
                    __builtin_bit_cast(short8, elo), acc[nt], 0, 0, 0);
            }
        if (mat == 0) {
            #pragma unroll
            for (int nt = 0; nt < 4; ++nt)
                #pragma unroll
                for (int rr = 0; rr < 4; ++rr)
                    yqh[(size_t)idxq[rr] + nt * 16] = f2bf(acc[nt][rr] + svq_l[nt]);
        } else {
            #pragma unroll
            for (int nt = 0; nt < 4; ++nt)
                #pragma unroll
                for (int rr = 0; rr < 4; ++rr)
                    kfrag[idxk[rr] + nt * 256] = f2bf(acc[nt][rr] + sv_l[nt]);
        }
    }
    {
        const unsigned short* mh = packs + 2 * 8192;
        const unsigned short* ml = mh + 4096;
        f32x4 acc[4] = {};
        #pragma unroll
        for (int kc = 0; kc < 2; ++kc)
            #pragma unroll
            for (int mt = 0; mt < 4; ++mt) {
                const int off = (mt * 16 + l15) * 64 + kc * 32 + quad * 8;
                u32x4 ehi = *(const u32x4*)(mh + off);
                u32x4 elo = *(const u32x4*)(ml + off);
                acc[mt] = __builtin_amdgcn_mfma_f32_16x16x32_bf16(
                    __builtin_bit_cast(short8, ehi),
                    __builtin_bit_cast(short8, xhi[kc]), acc[mt], 0, 0, 0);
                acc[mt] = __builtin_amdgcn_mfma_f32_16x16x32_bf16(
                    __builtin_bit_cast(short8, ehi),
                    __builtin_bit_cast(short8, xlo[kc]), acc[mt], 0, 0, 0);
                acc[mt] = __builtin_amdgcn_mfma_f32_16x16x32_bf16(
                    __builtin_bit_cast(short8, elo),
                    __builtin_bit_cast(short8, xhi[kc]), acc[mt], 0, 0, 0);
            }
        #pragma unroll
        for (int mt = 0; mt < 4; ++mt)
            #pragma unroll
            for (int rr = 0; rr < 4; ++rr) {
                const int dd = dbase + mt * 16 + quad * 4 + rr;
                vfrag[vbase + (dd >> 4) * 512 + (dd & 15) * 32] =
                    f2bf(acc[mt][rr] + svA[mt][rr]);
            }
    }
}

// ---------------------------------------------------------------------------
// K2 k_attn: NO-LDS flash attention.  All K/V fragment loads are contiguous
// 1KB wave transactions from the pre-fragmented global layouts; the 4-wave
// intra-block duplication of K is served by L1.  Zero barriers in the main
// loop (accumulator-only carried deps).  Grid 512 = 16 bh x 32 q-tiles
// (32 rows); waves = (qh, dh).  No-max softmax, quad-shuffle P transpose,
// fused output projection epilogue (wave-private LDS only).
// ---------------------------------------------------------------------------
__global__ __launch_bounds__(256) void k_attn(
    const unsigned short* __restrict__ yqh, const unsigned short* __restrict__ kfrag,
    const unsigned short* __restrict__ vfrag,
    const float* __restrict__ xbar, const float* __restrict__ vw,
    const int* __restrict__ embed_id, const float* __restrict__ sv_g,
    const float* __restrict__ gate,
    const unsigned short* __restrict__ packs,
    const float* __restrict__ ow, const float* __restrict__ ob,
    float* __restrict__ out)
{
    __shared__ __align__(16) unsigned short yst_s[4 * 4352];   // 34816 B
    __shared__ float vbar_s[128];
    __shared__ float vproj_s[128];

    const int tid  = threadIdx.x;
    const int w    = tid >> 6;
    const int lane = tid & 63;
    const int quad = lane >> 4;
    const int l15  = lane & 15;
    const int bh = blockIdx.x & 15, qt = blockIdx.x >> 4;
    const int b = bh >> 2, h = bh & 3;
    const int s0 = qt * 32;
    const int qh = w >> 1;
    const int dh = w & 1;

    const unsigned short* kb = kfrag + (size_t)bh * 131072;
    const unsigned short* vb = vfrag + (size_t)bh * 131072;
    const float gf = 1.f / (1.f + __expf(-gate[h]));

    // ---- vbar prologue (pos branch, rank-1 reconstruction) ----
    if (tid < 128) {
        const int c = tid & 63, wloc = tid >> 6;
        const float* ver = vw + embed_id[0] * 4096 + c * 64;
        const float* xbr = xbar + (b * 8 + h * 2 + wloc) * 64;
        float a = sv_g[c];
        #pragma unroll
        for (int j4 = 0; j4 < 16; ++j4) {
            f32x4 e4 = *(const f32x4*)(ver + j4 * 4);
            f32x4 x4 = *(const f32x4*)(xbr + j4 * 4);
            a += e4[0] * x4[0] + e4[1] * x4[1] + e4[2] * x4[2] + e4[3] * x4[3];
        }
        vbar_s[wloc * 64 + c] = a;
    }
    __syncthreads();
    // ---- vproj = gf*(vbar_dh @ ow^T) + ob ----
    if (tid < 128) {
        const int cp = tid & 63, w2 = tid >> 6;
        const float* owr = ow + cp * 64;
        const float* vbp = vbar_s + w2 * 64;
        float a = 0.f;
        #pragma unroll
        for (int j4 = 0; j4 < 16; ++j4) {
            f32x4 o4 = *(const f32x4*)(owr + j4 * 4);
            f32x4 v4 = *(const f32x4*)(vbp + j4 * 4);
            a += o4[0] * v4[0] + o4[1] * v4[1] + o4[2] * v4[2] + o4[3] * v4[3];
        }
        vproj_s[tid] = gf * a + ob[cp];
    }
    __syncthreads();

    // ---- Q fragments: B[n=q(l15)][k=d] ----
    u32x4 qf[4];
    #pragma unroll
    for (int kc = 0; kc < 4; ++kc)
        qf[kc] = *(const u32x4*)(yqh + (size_t)bh * 131072
                 + (s0 + qh * 16 + l15) * 128 + kc * 32 + quad * 8);

    // fragment load addresses (lane part)
    const int kl = quad * 128 + l15 * 8;       // within a (tt16, kc) 1KB chunk group
    const int vl = l15 * 32 + quad * 8;        // within a (it, dgrp) 512-short chunk

    f32x4 o[4] = {};
    float lsum = 0.f;
    const int srcA = ((quad & 1) << 5) + l15;

    // preload it = 0
    u32x4 k0c[4], k1c[4], vvc[4];
    #pragma unroll
    for (int kc = 0; kc < 4; ++kc) {
        k0c[kc] = *(const u32x4*)(kb + kc * 512 + kl);
        k1c[kc] = *(const u32x4*)(kb + 2048 + kc * 512 + kl);
    }
    #pragma unroll
    for (int dt = 0; dt < 4; ++dt)
        vvc[dt] = *(const u32x4*)(vb + (dh * 4 + dt) * 512 + vl);

    #pragma unroll 2
    for (int it = 0; it < 32; ++it) {
        u32x4 k0n[4], k1n[4], vvn[4];
        if (it < 31) {
            const unsigned short* kbn = kb + (size_t)(it + 1) * 4096;
            const unsigned short* vbn = vb + (size_t)(it + 1) * 4096;
            #pragma unroll
            for (int kc = 0; kc < 4; ++kc) {
                k0n[kc] = *(const u32x4*)(kbn + kc * 512 + kl);
                k1n[kc] = *(const u32x4*)(kbn + 2048 + kc * 512 + kl);
            }
            #pragma unroll
            for (int dt = 0; dt < 4; ++dt)
                vvn[dt] = *(const u32x4*)(vbn + (dh * 4 + dt) * 512 + vl);
        }

        // ---- S^T = K Q^T over two 16-t subtiles ----
        f32x4 sa0 = {}, sa1 = {};
        #pragma unroll
        for (int kc = 0; kc < 4; ++kc)
            sa0 = __builtin_amdgcn_mfma_f32_16x16x32_bf16(
                __builtin_bit_cast(short8, k0c[kc]),
                __builtin_bit_cast(short8, qf[kc]), sa0, 0, 0, 0);
        #pragma unroll
        for (int kc = 0; kc < 4; ++kc)
            sa1 = __builtin_amdgcn_mfma_f32_16x16x32_bf16(
                __builtin_bit_cast(short8, k1c[kc]),
                __builtin_bit_cast(short8, qf[kc]), sa1, 0, 0, 0);

        // p = exp(S - C); per-lane l partial (lane l15 = q-row)
        float p0[4], p1[4];
        #pragma unroll
        for (int r = 0; r < 4; ++r) {
            p0[r] = __expf(sa0[r] - SOFT_C);
            p1[r] = __expf(sa1[r] - SOFT_C);
            lsum += p0[r] + p1[r];
        }

        // P (C-layout) -> B-frag of PV^T via quad-permute shuffles
        unsigned int pk00 = (unsigned int)f2bf(p0[0]) | ((unsigned int)f2bf(p0[1]) << 16);
        unsigned int pk01 = (unsigned int)f2bf(p0[2]) | ((unsigned int)f2bf(p0[3]) << 16);
        unsigned int pk10 = (unsigned int)f2bf(p1[0]) | ((unsigned int)f2bf(p1[1]) << 16);
        unsigned int pk11 = (unsigned int)f2bf(p1[2]) | ((unsigned int)f2bf(p1[3]) << 16);
        unsigned int sel0 = (quad < 2) ? pk00 : pk10;
        unsigned int sel1 = (quad < 2) ? pk01 : pk11;
        u32x4 pf;
        pf[0] = (unsigned int)__shfl((int)sel0, srcA);
        pf[1] = (unsigned int)__shfl((int)sel1, srcA);
        pf[2] = (unsigned int)__shfl((int)sel0, srcA + 16);
        pf[3] = (unsigned int)__shfl((int)sel1, srcA + 16);

        // O^T += V^T P^T  (A = V frag, m = d)
        #pragma unroll
        for (int dt = 0; dt < 4; ++dt)
            o[dt] = __builtin_amdgcn_mfma_f32_16x16x32_bf16(
                __builtin_bit_cast(short8, vvc[dt]),
                __builtin_bit_cast(short8, pf), o[dt], 0, 0, 0);

        #pragma unroll
        for (int kc = 0; kc < 4; ++kc) { k0c[kc] = k0n[kc]; k1c[kc] = k1n[kc]; }
        #pragma unroll
        for (int dt = 0; dt < 4; ++dt) vvc[dt] = vvn[dt];
    }

    // ---- epilogue: fold l across quads, fused out-projection ----
    lsum += __shfl_xor(lsum, 16);
    lsum += __shfl_xor(lsum, 32);
    const float cf = (1.f - gf) / lsum;

    unsigned short* yst = yst_s + w * 4352;   // hi: [q][68], lo at +1088
    #pragma unroll
    for (int dt = 0; dt < 4; ++dt) {
        unsigned int hh[4];
        unsigned short ll[4];
        #pragma unroll
        for (int r = 0; r < 4; ++r) {
            float y = cf * o[dt][r];
            hh[r] = f2bf(y);
            ll[r] = f2bf(y - bf2f(hh[r]));
        }
        const int dloc = dt * 16 + quad * 4;
        u32x2 ph_, pl_;
        ph_[0] = hh[0] | (hh[1] << 16);
        ph_[1] = hh[2] | (hh[3] << 16);
        pl_[0] = (unsigned int)ll[0] | ((unsigned int)ll[1] << 16);
        pl_[1] = (unsigned int)ll[2] | ((unsigned int)ll[3] << 16);
        *(u32x2*)&yst[l15 * 68 + dloc] = ph_;
        *(u32x2*)&yst[1088 + l15 * 68 + dloc] = pl_;
    }
    u32x4 ybh[2], ybl[2];
    #pragma unroll
    for (int kc = 0; kc < 2; ++kc) {
        ybh[kc] = *(const u32x4*)&yst[l15 * 68 + kc * 32 + quad * 8];
        ybl[kc] = *(const u32x4*)&yst[1088 + l15 * 68 + kc * 32 + quad * 8];
    }
    const unsigned short* owh = packs + 3 * 8192;
    const unsigned short* owl = owh + 4096;
    f32x4 accp[4] = {};
    #pragma unroll
    for (int kc = 0; kc < 2; ++kc)
        #pragma unroll
        for (int mt = 0; mt < 4; ++mt) {
            const int off = (mt * 16 + l15) * 64 + kc * 32 + quad * 8;
            u32x4 ahi = *(const u32x4*)(owh + off);
            u32x4 alo = *(const u32x4*)(owl + off);
            accp[mt] = __builtin_amdgcn_mfma_f32_16x16x32_bf16(
                __builtin_bit_cast(short8, ahi),
                __builtin_bit_cast(short8, ybh[kc]), accp[mt], 0, 0, 0);
            accp[mt] = __builtin_amdgcn_mfma_f32_16x16x32_bf16(
                __builtin_bit_cast(short8, ahi),
                __builtin_bit_cast(short8, ybl[kc]), accp[mt], 0, 0, 0);
            accp[mt] = __builtin_amdgcn_mfma_f32_16x16x32_bf16(
                __builtin_bit_cast(short8, alo),
                __builtin_bit_cast(short8, ybh[kc]), accp[mt], 0, 0, 0);
        }
    const int sQ = s0 + qh * 16 + l15;
    float* op = out + ((size_t)((b * S_ + sQ) * 8 + 2 * h + dh)) * 64;
    #pragma unroll
    for (int mt = 0; mt < 4; ++mt) {
        f32x4 vp = *(const f32x4*)&vproj_s[dh * 64 + mt * 16 + quad * 4];
        f32x4 rv = accp[mt] + vp;
        *(f32x4*)(op + mt * 16 + quad * 4) = rv;
    }
}

extern "C" void kernel_launch(void* const* d_in, const int* in_sizes, int n_in,
                              void* d_out, int out_size, void* d_ws, size_t ws_size,
                              hipStream_t stream) {
    (void)in_sizes; (void)n_in; (void)out_size; (void)ws_size;
    const float* x        = (const float*)d_in[0];
    const float* pos      = (const float*)d_in[1];
    const float* strength = (const float*)d_in[2];
    const int*   embed_id = (const int*)d_in[3];
    const float* qw       = (const float*)d_in[4];
    const float* kw       = (const float*)d_in[5];
    const float* vw       = (const float*)d_in[6];
    const float* pw1      = (const float*)d_in[7];
    const float* pb1      = (const float*)d_in[8];
    const float* pw2      = (const float*)d_in[9];
    const float* pb2      = (const float*)d_in[10];
    const float* head_w   = (const float*)d_in[11];
    const float* gate     = (const float*)d_in[13];
    const float* out_w    = (const float*)d_in[14];
    const float* out_b    = (const float*)d_in[15];
    const float* str_w    = (const float*)d_in[16];
    const float* str_b    = (const float*)d_in[17];
    float* out = (float*)d_out;

    unsigned short* yqh   = (unsigned short*)d_ws;         // 4 MiB
    unsigned short* kfrag = yqh + 2097152;                 // 4 MiB
    unsigned short* vfrag = kfrag + 2097152;               // 4 MiB
    unsigned short* packs = vfrag + 2097152;               // 8 x 4096 shorts
    float* sv   = (float*)(packs + 8 * 4096);              // 64
    float* svq  = sv + 64;                                 // 64
    float* p_g  = svq + 64;                                // 16384
    float* xbar = p_g + 16384;                             // 2048

    k_prep<<<9, 256, 0, stream>>>(embed_id, qw, kw, vw, out_w, pos,
                                  pw1, pb1, pw2, pb2, head_w,
                                  strength, str_w, str_b, packs, sv, svq, p_g);
    k_qkv<<<768, 256, 0, stream>>>(x, packs, sv, svq, p_g, yqh, kfrag, vfrag, xbar);
    k_attn<<<512, 256, 0, stream>>>(yqh, kfrag, vfrag, xbar, vw, embed_id, sv,
                                    gate, packs, out_w, out_b, out);
}